// Round 10
// baseline (115.535 us; speedup 1.0000x reference)
//
#include <hip/hip_runtime.h>
#include <hip/hip_bf16.h>
#if !__has_builtin(__builtin_amdgcn_cvt_pk_fp8_f32)
#include <hip/hip_fp8.h>
#endif

typedef unsigned char u8;
typedef long long i64;
typedef i64 i64x2 __attribute__((ext_vector_type(2)));
typedef float f32x4 __attribute__((ext_vector_type(4)));

#define NROW 8192
#define NHALF 4096
#define DIM 256
#define TILES 64                       // 8192 / 128
#define NBLK (TILES * (TILES + 1) / 2) // 2080 upper-triangular tiles
#define PBLK 512                       // k_prep blocks (one 16-row strip each)

// gbuf float offsets (all cross-block state accessed via atomics only):
#define G_COL 0    // [0..255] column sums
#define G_SS 256   // sum of |x|^2
#define G_CNT1 260 // k_mid completion counter (unsigned)
#define G_CNT2 264 // k_main completion counter (unsigned)
#define G_C4 272   // bandwidth scalar (written by k_mid last block, cross-kernel)
#define G_ACC 288  // 32 accumulator slots, 16 floats apart

static __device__ __forceinline__ float fast_exp2(float x) {
#if __has_builtin(__builtin_amdgcn_exp2f)
  return __builtin_amdgcn_exp2f(x);
#else
  return exp2f(x);
#endif
}

// pack 4 floats -> 4 OCP e4m3 bytes (RNE, saturating) [k ascending in bytes]
static __device__ __forceinline__ unsigned pack4_fp8(float4 v) {
#if __has_builtin(__builtin_amdgcn_cvt_pk_fp8_f32)
  int p = 0;
  p = __builtin_amdgcn_cvt_pk_fp8_f32(v.x, v.y, p, false); // bytes 0,1
  p = __builtin_amdgcn_cvt_pk_fp8_f32(v.z, v.w, p, true);  // bytes 2,3
  return (unsigned)p;
#else
  __hip_fp8_e4m3 a(v.x), b(v.y), c(v.z), d(v.w);
  return (unsigned)a.__x | ((unsigned)b.__x << 8) | ((unsigned)c.__x << 16) |
         ((unsigned)d.__x << 24);
#endif
}

// Fragment-pair-major fp8 layout: element (row r, col k):
//   strip s=r>>4, pair p=k>>6, half h=(k>>5)&1, quad q=(k&31)>>3, j=k&7
//   byte index = ((s*4+p)*64 + q*16 + (r&15))*16 + h*8 + j
// One wave dwordx4 load at fp=(s*4+p), lane L=q*16+(r&15) yields TWO MFMA A/B
// fragments (chunks 2p, 2p+1): lane holds row s*16+(L&15), k=(L>>4)*8+j.

// ---------------- K1: fp32->fp8 swizzled store + row |x|^2 + col partials ---
// Block 0 additionally zero-inits all gbuf scalar state via atomicExch.
__global__ void k_prep(const float* __restrict__ src, const float* __restrict__ tgt,
                       u8* __restrict__ Xq, float* __restrict__ sq,
                       float* __restrict__ colpart, float* __restrict__ gbuf) {
  __shared__ float cps[4][DIM];
  int w = threadIdx.x >> 6, lane = threadIdx.x & 63;
  int s = blockIdx.x;
  int cc = threadIdx.x;
  if (s == 0) { // zero shared state (k_prep completes before k_mid launches)
    if (cc <= G_SS) atomicExch(gbuf + cc, 0.f);
    if (cc == 0) {
      atomicExch((unsigned*)(gbuf + G_CNT1), 0u);
      atomicExch((unsigned*)(gbuf + G_CNT2), 0u);
    }
    if (cc < 32) atomicExch(gbuf + G_ACC + cc * 16, 0.f);
  }
  int r0 = s * 16 + w * 4;
  // this lane covers k in [4*lane, 4*lane+4)
  int p = lane >> 4, h = (lane >> 3) & 1, q = (lane >> 1) & 3, j = 4 * (lane & 1);
  float4 ca = make_float4(0.f, 0.f, 0.f, 0.f);
#pragma unroll
  for (int rr = 0; rr < 4; ++rr) {
    int row = r0 + rr;
    const float* pp = (row < NHALF) ? (src + (size_t)row * DIM)
                                    : (tgt + (size_t)(row - NHALF) * DIM);
    float4 v = *(const float4*)(pp + lane * 4);
    size_t di = ((size_t)(s * 4 + p) * 64 + q * 16 + (row & 15)) * 16 + h * 8 + j;
    *(unsigned*)(Xq + di) = pack4_fp8(v);
    ca.x += v.x; ca.y += v.y; ca.z += v.z; ca.w += v.w;
    float sum = v.x * v.x + v.y * v.y + v.z * v.z + v.w * v.w;
#pragma unroll
    for (int off = 32; off > 0; off >>= 1) sum += __shfl_down(sum, off);
    if (lane == 0) sq[row] = sum;
  }
  cps[w][lane * 4 + 0] = ca.x;
  cps[w][lane * 4 + 1] = ca.y;
  cps[w][lane * 4 + 2] = ca.z;
  cps[w][lane * 4 + 3] = ca.w;
  __syncthreads();
  colpart[blockIdx.x * DIM + cc] = cps[0][cc] + cps[1][cc] + cps[2][cc] + cps[3][cc];
}

// ---------------- K2: fold partials + bandwidth scalar (fused k_red+k_scal) -
// 32 blocks x 256 threads. Atomics-only cross-block state; last block (via
// completion counter) computes c4. 32-deep column atomics are cheap (round-6's
// regression was 512-deep).
__global__ void k_mid(const float* __restrict__ colpart, const float* __restrict__ sq,
                      float* __restrict__ gbuf) {
  int b = blockIdx.x, c = threadIdx.x, lane = c & 63, w = c >> 6;
  __shared__ float rs[4];
  __shared__ unsigned oldc;
  float s = 0.f;
#pragma unroll
  for (int i = 0; i < 16; ++i) s += colpart[(size_t)(b * 16 + i) * DIM + c];
  atomicAdd(gbuf + G_COL + c, s); // 32-deep per column
  float qv = sq[b * DIM + c];
#pragma unroll
  for (int off = 32; off > 0; off >>= 1) qv += __shfl_down(qv, off);
  if (lane == 0) rs[w] = qv;
  __syncthreads();
  if (c == 0) {
    atomicAdd(gbuf + G_SS, rs[0] + rs[1] + rs[2] + rs[3]);
    __threadfence(); // order the adds before the counter
    oldc = atomicAdd((unsigned*)(gbuf + G_CNT1), 1u);
  }
  __syncthreads();
  if (oldc == 31) { // last block: compute c4 (block-uniform branch)
    float v = atomicAdd(gbuf + G_COL + c, 0.f); // coherent colsum read
    float vn = v * v;
#pragma unroll
    for (int off = 32; off > 0; off >>= 1) vn += __shfl_down(vn, off);
    __syncthreads(); // rs reuse
    if (lane == 0) rs[w] = vn;
    __syncthreads();
    if (c == 0) {
      double VN = (double)rs[0] + rs[1] + rs[2] + rs[3];
      double S  = (double)atomicAdd(gbuf + G_SS, 0.f);
      double suml2 = 2.0 * (double)NROW * S - 2.0 * VN;
      double bw = suml2 / ((double)NROW * NROW - NROW) / 4.0; // / 2^(KN/2)
      gbuf[G_C4] = (float)(1.4426950408889634 / (bw * 16.0)); // cross-kernel
    }
  }
}

// ---------------- K3: fused fp8 X*X^T + multi-RBF epilogue + signed reduce --
// 2080 blocks (upper-tri 128x128 tiles) x 256 threads (4 waves, 2x2 of 64x64).
// Round-5/9 proven inner structure, byte-identical; only the tail gains a
// done-counter so the last block emits the final scalar (k_fin folded in).
__global__ __launch_bounds__(256, 4) void k_main(const u8* __restrict__ Xq,
                                                 const float* __restrict__ sq,
                                                 float* __restrict__ gbuf,
                                                 float* __restrict__ out) {
  __shared__ float red[4];
  __shared__ bool lastb;

  // linear triangle index -> (bi, bj), bj >= bi
  int bi = 0, rem = blockIdx.x;
  while (rem >= TILES - bi) { rem -= TILES - bi; ++bi; }
  int bj = bi + rem;

  int tid = threadIdx.x;
  int w = tid >> 6, lane = tid & 63;
  int wi = w >> 1, wj = w & 1;

  f32x4 acc[4][4];
#pragma unroll
  for (int a = 0; a < 4; ++a)
#pragma unroll
    for (int b = 0; b < 4; ++b) acc[a][b] = (f32x4){0.f, 0.f, 0.f, 0.f};

  const i64x2* X2 = (const i64x2*)Xq; // fragment-pair fp: X2[fp*64 + lane]
  const int sA = bi * 8 + wi * 4;     // this wave's 4 A-strips
  const int sB = bj * 8 + wj * 4;     // this wave's 4 B-strips

#pragma unroll
  for (int p = 0; p < 4; ++p) {
    i64x2 aP[4], bP[4];
#pragma unroll
    for (int mi = 0; mi < 4; ++mi)
      aP[mi] = X2[(size_t)((sA + mi) * 4 + p) * 64 + lane];
#pragma unroll
    for (int ni = 0; ni < 4; ++ni)
      bP[ni] = X2[(size_t)((sB + ni) * 4 + p) * 64 + lane];
#pragma unroll
    for (int mi = 0; mi < 4; ++mi)
#pragma unroll
      for (int ni = 0; ni < 4; ++ni)
        acc[mi][ni] = __builtin_amdgcn_mfma_f32_16x16x32_fp8_fp8(
            aP[mi].x, bP[ni].x, acc[mi][ni], 0, 0, 0);
#pragma unroll
    for (int mi = 0; mi < 4; ++mi)
#pragma unroll
      for (int ni = 0; ni < 4; ++ni)
        acc[mi][ni] = __builtin_amdgcn_mfma_f32_16x16x32_fp8_fp8(
            aP[mi].y, bP[ni].y, acc[mi][ni], 0, 0, 0);
  }

  // Epilogue: l2 -> t + t^2 + t^4 + t^8 + t^16, signed sum.
  // C/D layout: col = lane&15, row = (lane>>4)*4 + reg (dtype-independent).
  float c4 = gbuf[G_C4];
  float wgt = ((bi < 32) == (bj < 32)) ? 1.f : -1.f; // quadrant sign s_i*s_j
  if (bi != bj) wgt *= 2.f;                          // symmetry: count (j,i) too
  bool diag = (bi == bj);
  int ib = bi * 128 + wi * 64 + (lane >> 4) * 4;
  int jb = bj * 128 + wj * 64 + (lane & 15);
  f32x4 sqi[4];
#pragma unroll
  for (int mi = 0; mi < 4; ++mi) sqi[mi] = *(const f32x4*)(sq + ib + mi * 16);
  float lsum = 0.f;
#pragma unroll
  for (int ni = 0; ni < 4; ++ni) {
    float sqj = sq[jb + ni * 16];
#pragma unroll
    for (int mi = 0; mi < 4; ++mi) {
#pragma unroll
      for (int r = 0; r < 4; ++r) {
        float l2 = sqi[mi][r] + sqj - 2.f * acc[mi][ni][r];
        float t  = fast_exp2(-l2 * c4);
        float t2 = t * t, t4 = t2 * t2, t8 = t4 * t4, t16 = t8 * t8;
        float tt = t + t2 + t4 + t8 + t16;
        // exact diagonal: K_ii = 5 (kills fp8 quantization bias on l2_ii)
        if (diag && (ib + mi * 16 + r) == (jb + ni * 16)) tt = 5.f;
        lsum += tt;
      }
    }
  }
#pragma unroll
  for (int off = 32; off > 0; off >>= 1) lsum += __shfl_down(lsum, off);
  if (lane == 0) red[w] = lsum;
  __syncthreads();
  if (tid == 0) {
    atomicAdd(gbuf + G_ACC + (blockIdx.x & 31) * 16,
              wgt * (red[0] + red[1] + red[2] + red[3]));
    __threadfence(); // order slot-add before counter-add
    unsigned old = atomicAdd((unsigned*)(gbuf + G_CNT2), 1u);
    lastb = (old == NBLK - 1);
  }
  __syncthreads();
  if (lastb && w == 0) { // last block, wave 0: final reduce (coherent atomic reads)
    float s = (lane < 32) ? atomicAdd(gbuf + G_ACC + lane * 16, 0.f) : 0.f;
#pragma unroll
    for (int off = 32; off > 0; off >>= 1) s += __shfl_down(s, off);
    if (lane == 0) out[0] = s / 16777216.f; // / 4096^2
  }
}

extern "C" void kernel_launch(void* const* d_in, const int* in_sizes, int n_in,
                              void* d_out, int out_size, void* d_ws, size_t ws_size,
                              hipStream_t stream) {
  const float* src = (const float*)d_in[0];
  const float* tgt = (const float*)d_in[1];
  char* ws = (char*)d_ws;
  u8* Xq = (u8*)ws;                                      // 2 MiB swizzled fp8
  size_t off = (size_t)NROW * DIM;
  float* sq = (float*)(ws + off);      off += NROW * 4;  // 32 KiB row |x|^2
  float* colpart = (float*)(ws + off); off += (size_t)PBLK * DIM * 4; // 512 KiB
  float* gbuf = (float*)(ws + off);    // colsum/ss/counters/c4/acc slots
  float* out = (float*)d_out;

  k_prep<<<PBLK, 256, 0, stream>>>(src, tgt, Xq, sq, colpart, gbuf);
  k_mid<<<32, 256, 0, stream>>>(colpart, sq, gbuf);
  k_main<<<NBLK, 256, 0, stream>>>(Xq, sq, gbuf, out);
}

// Round 11
// 89.283 us; speedup vs baseline: 1.2940x; 1.2940x over previous
//
#include <hip/hip_runtime.h>
#include <hip/hip_bf16.h>
#if !__has_builtin(__builtin_amdgcn_cvt_pk_fp8_f32)
#include <hip/hip_fp8.h>
#endif

typedef unsigned char u8;
typedef long long i64;
typedef i64 i64x2 __attribute__((ext_vector_type(2)));
typedef float f32x4 __attribute__((ext_vector_type(4)));

#define NROW 8192
#define NHALF 4096
#define DIM 256
#define TILES 64                       // 8192 / 128
#define NBLK (TILES * (TILES + 1) / 2) // 2080 upper-triangular tiles
#define PBLK 512                       // k_prep blocks (one 16-row strip each)

// gbuf float offsets:
#define G_COL 0    // [0..255] column sums (atomic)
#define G_SS 256   // sum of |x|^2 (atomic)
#define G_CNT1 260 // k_mid completion counter (unsigned)
#define G_C4 272   // bandwidth scalar == round-9 "scal[0]" (scal = gbuf+G_C4)
#define G_ACC 288  // 32 accumulator slots, 16 floats apart (== scal+16+s*16)

static __device__ __forceinline__ float fast_exp2(float x) {
#if __has_builtin(__builtin_amdgcn_exp2f)
  return __builtin_amdgcn_exp2f(x);
#else
  return exp2f(x);
#endif
}

// pack 4 floats -> 4 OCP e4m3 bytes (RNE, saturating) [k ascending in bytes]
static __device__ __forceinline__ unsigned pack4_fp8(float4 v) {
#if __has_builtin(__builtin_amdgcn_cvt_pk_fp8_f32)
  int p = 0;
  p = __builtin_amdgcn_cvt_pk_fp8_f32(v.x, v.y, p, false); // bytes 0,1
  p = __builtin_amdgcn_cvt_pk_fp8_f32(v.z, v.w, p, true);  // bytes 2,3
  return (unsigned)p;
#else
  __hip_fp8_e4m3 a(v.x), b(v.y), c(v.z), d(v.w);
  return (unsigned)a.__x | ((unsigned)b.__x << 8) | ((unsigned)c.__x << 16) |
         ((unsigned)d.__x << 24);
#endif
}

// Fragment-pair-major fp8 layout: element (row r, col k):
//   strip s=r>>4, pair p=k>>6, half h=(k>>5)&1, quad q=(k&31)>>3, j=k&7
//   byte index = ((s*4+p)*64 + q*16 + (r&15))*16 + h*8 + j
// One wave dwordx4 load at fp=(s*4+p), lane L=q*16+(r&15) yields TWO MFMA A/B
// fragments (chunks 2p, 2p+1): lane holds row s*16+(L&15), k=(L>>4)*8+j.

// ---------------- K1: fp32->fp8 swizzled store + row |x|^2 + col partials ---
// (round-10 form, measured ~as part of 18.6 µs chain)
__global__ void k_prep(const float* __restrict__ src, const float* __restrict__ tgt,
                       u8* __restrict__ Xq, float* __restrict__ sq,
                       float* __restrict__ colpart, float* __restrict__ gbuf) {
  __shared__ float cps[4][DIM];
  int w = threadIdx.x >> 6, lane = threadIdx.x & 63;
  int s = blockIdx.x;
  int cc = threadIdx.x;
  if (s == 0) { // zero shared state (k_prep completes before k_mid launches)
    if (cc <= G_SS) atomicExch(gbuf + cc, 0.f);
    if (cc == 0) atomicExch((unsigned*)(gbuf + G_CNT1), 0u);
    if (cc < 32) atomicExch(gbuf + G_ACC + cc * 16, 0.f);
  }
  int r0 = s * 16 + w * 4;
  // this lane covers k in [4*lane, 4*lane+4)
  int p = lane >> 4, h = (lane >> 3) & 1, q = (lane >> 1) & 3, j = 4 * (lane & 1);
  float4 ca = make_float4(0.f, 0.f, 0.f, 0.f);
#pragma unroll
  for (int rr = 0; rr < 4; ++rr) {
    int row = r0 + rr;
    const float* pp = (row < NHALF) ? (src + (size_t)row * DIM)
                                    : (tgt + (size_t)(row - NHALF) * DIM);
    float4 v = *(const float4*)(pp + lane * 4);
    size_t di = ((size_t)(s * 4 + p) * 64 + q * 16 + (row & 15)) * 16 + h * 8 + j;
    *(unsigned*)(Xq + di) = pack4_fp8(v);
    ca.x += v.x; ca.y += v.y; ca.z += v.z; ca.w += v.w;
    float sum = v.x * v.x + v.y * v.y + v.z * v.z + v.w * v.w;
#pragma unroll
    for (int off = 32; off > 0; off >>= 1) sum += __shfl_down(sum, off);
    if (lane == 0) sq[row] = sum;
  }
  cps[w][lane * 4 + 0] = ca.x;
  cps[w][lane * 4 + 1] = ca.y;
  cps[w][lane * 4 + 2] = ca.z;
  cps[w][lane * 4 + 3] = ca.w;
  __syncthreads();
  colpart[blockIdx.x * DIM + cc] = cps[0][cc] + cps[1][cc] + cps[2][cc] + cps[3][cc];
}

// ---------------- K2: fold partials + bandwidth scalar (round-10 form) ------
__global__ void k_mid(const float* __restrict__ colpart, const float* __restrict__ sq,
                      float* __restrict__ gbuf) {
  int b = blockIdx.x, c = threadIdx.x, lane = c & 63, w = c >> 6;
  __shared__ float rs[4];
  __shared__ unsigned oldc;
  float s = 0.f;
#pragma unroll
  for (int i = 0; i < 16; ++i) s += colpart[(size_t)(b * 16 + i) * DIM + c];
  atomicAdd(gbuf + G_COL + c, s); // 32-deep per column
  float qv = sq[b * DIM + c];
#pragma unroll
  for (int off = 32; off > 0; off >>= 1) qv += __shfl_down(qv, off);
  if (lane == 0) rs[w] = qv;
  __syncthreads();
  if (c == 0) {
    atomicAdd(gbuf + G_SS, rs[0] + rs[1] + rs[2] + rs[3]);
    __threadfence(); // order the adds before the counter
    oldc = atomicAdd((unsigned*)(gbuf + G_CNT1), 1u);
  }
  __syncthreads();
  if (oldc == 31) { // last block: compute c4 (block-uniform branch)
    float v = atomicAdd(gbuf + G_COL + c, 0.f); // coherent colsum read
    float vn = v * v;
#pragma unroll
    for (int off = 32; off > 0; off >>= 1) vn += __shfl_down(vn, off);
    __syncthreads(); // rs reuse
    if (lane == 0) rs[w] = vn;
    __syncthreads();
    if (c == 0) {
      double VN = (double)rs[0] + rs[1] + rs[2] + rs[3];
      double S  = (double)atomicAdd(gbuf + G_SS, 0.f);
      double suml2 = 2.0 * (double)NROW * S - 2.0 * VN;
      double bw = suml2 / ((double)NROW * NROW - NROW) / 4.0; // / 2^(KN/2)
      gbuf[G_C4] = (float)(1.4426950408889634 / (bw * 16.0)); // cross-kernel
    }
  }
}

// ---------------- K3: fused fp8 X*X^T + multi-RBF epilogue + signed reduce --
// BYTE-IDENTICAL to round 9's k_main (the 72-VGPR, load-batched schedule).
// 2080 blocks (upper-tri 128x128 tiles) x 256 threads (4 waves, 2x2 of 64x64).
__global__ __launch_bounds__(256, 4) void k_main(const u8* __restrict__ Xq,
                                                 const float* __restrict__ sq,
                                                 const float* __restrict__ scal,
                                                 float* __restrict__ accbuf) {
  __shared__ float red[4];

  // linear triangle index -> (bi, bj), bj >= bi
  int bi = 0, rem = blockIdx.x;
  while (rem >= TILES - bi) { rem -= TILES - bi; ++bi; }
  int bj = bi + rem;

  int tid = threadIdx.x;
  int w = tid >> 6, lane = tid & 63;
  int wi = w >> 1, wj = w & 1;

  f32x4 acc[4][4];
#pragma unroll
  for (int a = 0; a < 4; ++a)
#pragma unroll
    for (int b = 0; b < 4; ++b) acc[a][b] = (f32x4){0.f, 0.f, 0.f, 0.f};

  const i64x2* X2 = (const i64x2*)Xq; // fragment-pair fp: X2[fp*64 + lane]
  const int sA = bi * 8 + wi * 4;     // this wave's 4 A-strips
  const int sB = bj * 8 + wj * 4;     // this wave's 4 B-strips

#pragma unroll
  for (int p = 0; p < 4; ++p) {
    i64x2 aP[4], bP[4];
#pragma unroll
    for (int mi = 0; mi < 4; ++mi)
      aP[mi] = X2[(size_t)((sA + mi) * 4 + p) * 64 + lane];
#pragma unroll
    for (int ni = 0; ni < 4; ++ni)
      bP[ni] = X2[(size_t)((sB + ni) * 4 + p) * 64 + lane];
#pragma unroll
    for (int mi = 0; mi < 4; ++mi)
#pragma unroll
      for (int ni = 0; ni < 4; ++ni)
        acc[mi][ni] = __builtin_amdgcn_mfma_f32_16x16x32_fp8_fp8(
            aP[mi].x, bP[ni].x, acc[mi][ni], 0, 0, 0);
#pragma unroll
    for (int mi = 0; mi < 4; ++mi)
#pragma unroll
      for (int ni = 0; ni < 4; ++ni)
        acc[mi][ni] = __builtin_amdgcn_mfma_f32_16x16x32_fp8_fp8(
            aP[mi].y, bP[ni].y, acc[mi][ni], 0, 0, 0);
  }

  // Epilogue: l2 -> t + t^2 + t^4 + t^8 + t^16, signed sum.
  // C/D layout: col = lane&15, row = (lane>>4)*4 + reg (dtype-independent).
  float c4 = scal[0];
  float wgt = ((bi < 32) == (bj < 32)) ? 1.f : -1.f; // quadrant sign s_i*s_j
  if (bi != bj) wgt *= 2.f;                          // symmetry: count (j,i) too
  bool diag = (bi == bj);
  int ib = bi * 128 + wi * 64 + (lane >> 4) * 4;
  int jb = bj * 128 + wj * 64 + (lane & 15);
  f32x4 sqi[4];
#pragma unroll
  for (int mi = 0; mi < 4; ++mi) sqi[mi] = *(const f32x4*)(sq + ib + mi * 16);
  float lsum = 0.f;
#pragma unroll
  for (int ni = 0; ni < 4; ++ni) {
    float sqj = sq[jb + ni * 16];
#pragma unroll
    for (int mi = 0; mi < 4; ++mi) {
#pragma unroll
      for (int r = 0; r < 4; ++r) {
        float l2 = sqi[mi][r] + sqj - 2.f * acc[mi][ni][r];
        float t  = fast_exp2(-l2 * c4);
        float t2 = t * t, t4 = t2 * t2, t8 = t4 * t4, t16 = t8 * t8;
        float tt = t + t2 + t4 + t8 + t16;
        // exact diagonal: K_ii = 5 (kills fp8 quantization bias on l2_ii)
        if (diag && (ib + mi * 16 + r) == (jb + ni * 16)) tt = 5.f;
        lsum += tt;
      }
    }
  }
#pragma unroll
  for (int off = 32; off > 0; off >>= 1) lsum += __shfl_down(lsum, off);
  if (lane == 0) red[w] = lsum;
  __syncthreads();
  if (tid == 0)
    atomicAdd(accbuf + (blockIdx.x & 31) * 16,
              wgt * (red[0] + red[1] + red[2] + red[3]));
}

// ---------------- K4: finalize ----------------------------------------------
__global__ void k_fin(const float* __restrict__ accbuf, float* __restrict__ out) {
  int lane = threadIdx.x & 63;
  float s = (lane < 32) ? accbuf[lane * 16] : 0.f;
#pragma unroll
  for (int off = 32; off > 0; off >>= 1) s += __shfl_down(s, off);
  if (threadIdx.x == 0) out[0] = s / 16777216.f; // / 4096^2
}

extern "C" void kernel_launch(void* const* d_in, const int* in_sizes, int n_in,
                              void* d_out, int out_size, void* d_ws, size_t ws_size,
                              hipStream_t stream) {
  const float* src = (const float*)d_in[0];
  const float* tgt = (const float*)d_in[1];
  char* ws = (char*)d_ws;
  u8* Xq = (u8*)ws;                                      // 2 MiB swizzled fp8
  size_t off = (size_t)NROW * DIM;
  float* sq = (float*)(ws + off);      off += NROW * 4;  // 32 KiB row |x|^2
  float* colpart = (float*)(ws + off); off += (size_t)PBLK * DIM * 4; // 512 KiB
  float* gbuf = (float*)(ws + off);    // colsum/ss/counter/c4/acc slots
  float* out = (float*)d_out;

  k_prep<<<PBLK, 256, 0, stream>>>(src, tgt, Xq, sq, colpart, gbuf);
  k_mid<<<32, 256, 0, stream>>>(colpart, sq, gbuf);
  // round-9 k_main signature: scal = gbuf+G_C4 (scal[0]=c4), accbuf = gbuf+G_ACC
  k_main<<<NBLK, 256, 0, stream>>>(Xq, sq, gbuf + G_C4, gbuf + G_ACC);
  k_fin<<<1, 64, 0, stream>>>(gbuf + G_ACC, out);
}